// Round 4
// baseline (396.961 us; speedup 1.0000x reference)
//
#include <hip/hip_runtime.h>

#define NEG (-10000.0f)
#define START_TAG 62
#define STOP_TAG 63
#define SLEN 512
#define BATCH 512
#define NTAG 64

typedef float f32x2 __attribute__((ext_vector_type(2)));
typedef float f32x4 __attribute__((ext_vector_type(4)));

__device__ __forceinline__ float readlane_f(float v, int lane) {
    return __uint_as_float(__builtin_amdgcn_readlane(__float_as_uint(v), lane));
}

// One wave per TWO batches; lane j = tag j.
//
// Round-8: round 7 (exp-space, LDS-broadcast) got 186->125.8 us. Remaining
// wall 590 cyc/step vs ~200 busy -> the stall is the LDS roundtrip chain
// (ds_write q -> 16x ds_read_b128 (~190 cyc pipe) -> ~120 cyc return -> FMA
// tree). That is PIPE latency, not an SGPR issue hazard (round 2's failure
// mode), so independent VALU work CAN fill it: interleave TWO independent
// batch recursions per wave (grid 256). E matrix stays shared in VGPRs.
// Batch B's FMA tree fills batch A's DS wait and vice versa.
//
// Exp-space recursion per batch (identical math to round 7, verified):
//   acc_j = sum_i q_i * E_ij  (v_pk_fma over e2 pairs)
//   q'_j  = acc_j * exp(f_j) * rinv,  rinv = 2^-k exact from prior acc[lane0]
//   logz  = log(sum_j q_j e^tstop_j) + C0 + ktot*ln2
__global__ __launch_bounds__(64) __attribute__((amdgpu_waves_per_eu(1, 1)))
void crf_fwd(const float* __restrict__ feats,
             const int* __restrict__ tags,
             const float* __restrict__ mask,
             const float* __restrict__ trans,
             float* __restrict__ diff /* [BATCH] */) {
    const int bp = blockIdx.x; // batch pair 0..255
    const int bA = 2 * bp;
    const int bB = 2 * bp + 1;
    const int j = threadIdx.x; // tag lane 0..63

    __shared__ float2 smask2[SLEN];               // (maskA, maskB) per step
    __shared__ __align__(16) float qrA[2][NTAG];  // q ping-pong, batch A
    __shared__ __align__(16) float qrB[2][NTAG];  // q ping-pong, batch B

    // ---- E pairs in registers (shared by both batches) ----
    f32x2 e2[32];
    float colsum = 0.0f;
#pragma unroll
    for (int r = 0; r < 32; ++r) {
        float lo = __expf(trans[(2 * r) * NTAG + j]);     // exp(NEG) -> 0, desired
        float hi = __expf(trans[(2 * r + 1) * NTAG + j]);
        e2[r] = (f32x2){lo, hi};
        colsum += lo + hi;
    }
    const float tstop = trans[STOP_TAG * NTAG + j];

    // ---- mask columns preload (regs reused by epilogue 2) ----
    float mrA[8], mrB[8];
#pragma unroll
    for (int k = 0; k < 8; ++k) {
        mrA[k] = mask[(64 * k + j) * BATCH + bA];
        mrB[k] = mask[(64 * k + j) * BATCH + bB];
    }
#pragma unroll
    for (int k = 0; k < 8; ++k)
        smask2[64 * k + j] = make_float2(mrA[k], mrB[k]);

    // ---- step 0 (exact analytic; trans[START,:]==NEG) ----
    float fA0 = feats[(0 * BATCH + bA) * NTAG + j];
    float fB0 = feats[(0 * BATCH + bB) * NTAG + j];
    float m0A = readlane_f(mrA[0], 0);
    float m0B = readlane_f(mrB[0], 0);
    float cold = (j == START_TAG) ? 0.0f : NEG;
    float alpha0A = (m0A > 0.0f) ? (NEG + log1pf(colsum) + fA0) : cold;
    float alpha0B = (m0B > 0.0f) ? (NEG + log1pf(colsum) + fB0) : cold;
    const float C0A = readlane_f(alpha0A, START_TAG);
    const float C0B = readlane_f(alpha0B, START_TAG);
    float qA = __expf(alpha0A - C0A); // cold: all 0 except START lane = 1
    float qB = __expf(alpha0B - C0B);

    if (j == 0) smask2[0] = make_float2(0.0f, 0.0f); // s=0 is a masked no-op
    qrA[0][j] = qA;
    qrB[0][j] = qB;
    __syncthreads(); // single wave: cheap; orders LDS init before loop reads

    // ---- feats ring prefetch depth 8 per batch ----
    const float* fpA = feats + (size_t)bA * NTAG + j;
    const float* fpB = feats + (size_t)bB * NTAG + j;
    float frA[8], frB[8];
#pragma unroll
    for (int t = 0; t < 8; ++t) {
        frA[t] = fpA[(size_t)t * BATCH * NTAG];
        frB[t] = fpB[(size_t)t * BATCH * NTAG];
    }

    float rinvA = 1.0f, rinvB = 1.0f; // pending normalizers 2^-kcur
    int kcurA = 0, kcurB = 0;
    int ktotA = 0, ktotB = 0;

    for (int blk = 0; blk < 64; ++blk) {
#pragma unroll
        for (int t = 0; t < 8; ++t) {
            const int s = blk * 8 + t;
            const int ph = t & 1; // step parity == t parity (blk*8 even)

            const float2 mk2 = smask2[s]; // uniform ds_read_b64

            float efA = __expf(frA[t]); // operand loaded 8 steps ago
            float efB = __expf(frB[t]);
            int sp = s + 8;
            if (sp > SLEN - 1) sp = SLEN - 1; // tail garbage, never consumed
            frA[t] = fpA[(size_t)sp * BATCH * NTAG];
            frB[t] = fpB[(size_t)sp * BATCH * NTAG];
            float efrA = efA * rinvA; // off-chain (rinv known from last step)
            float efrB = efB * rinvB;

            // ---- acc_j = sum_i q_i * E_ij for BOTH batches, interleaved ----
            const f32x4* qvA = (const f32x4*)(&qrA[ph][0]);
            const f32x4* qvB = (const f32x4*)(&qrB[ph][0]);
            f32x2 aA[8], aB[8];
#pragma unroll
            for (int c = 0; c < 8; ++c) {
                aA[c] = (f32x2){0.0f, 0.0f};
                aB[c] = (f32x2){0.0f, 0.0f};
            }
#pragma unroll
            for (int r = 0; r < 16; ++r) {
                f32x4 a4 = qvA[r];
                f32x4 b4 = qvB[r];
                aA[(2 * r) & 7] = (f32x2){a4.x, a4.y} * e2[2 * r] + aA[(2 * r) & 7];
                aB[(2 * r) & 7] = (f32x2){b4.x, b4.y} * e2[2 * r] + aB[(2 * r) & 7];
                aA[(2 * r + 1) & 7] = (f32x2){a4.z, a4.w} * e2[2 * r + 1] + aA[(2 * r + 1) & 7];
                aB[(2 * r + 1) & 7] = (f32x2){b4.z, b4.w} * e2[2 * r + 1] + aB[(2 * r + 1) & 7];
            }
            f32x2 sA = ((aA[0] + aA[1]) + (aA[2] + aA[3])) +
                       ((aA[4] + aA[5]) + (aA[6] + aA[7]));
            f32x2 sB = ((aB[0] + aB[1]) + (aB[2] + aB[3])) +
                       ((aB[4] + aB[5]) + (aB[6] + aB[7]));
            float accA = sA.x + sA.y;
            float accB = sB.x + sB.y;

            float qnA = accA * efrA;
            float qnB = accB * efrB;
            bool updA = (mk2.x > 0.0f);
            bool updB = (mk2.y > 0.0f);
            qA = updA ? qnA : qA;
            qB = updB ? qnB : qB;
            qrA[ph ^ 1][j] = qA; // publish for next step (in-order DS pipe)
            qrB[ph ^ 1][j] = qB;

            // ---- renormalizer bookkeeping (off the critical chain) ----
            ktotA = updA ? (ktotA + kcurA) : ktotA;
            ktotB = updB ? (ktotB + kcurB) : ktotB;
            unsigned auA = __builtin_amdgcn_readfirstlane(__float_as_uint(accA));
            unsigned auB = __builtin_amdgcn_readfirstlane(__float_as_uint(accB));
            int keA = (int)((auA >> 23) & 0xffu) - 127;
            int keB = (int)((auB >> 23) & 0xffu) - 127;
            keA = (keA < -60) ? -60 : ((keA > 60) ? 60 : keA);
            keB = (keB < -60) ? -60 : ((keB > 60) ? 60 : keB);
            float rnA = __uint_as_float((unsigned)(127 - keA) << 23); // exact 2^-ke
            float rnB = __uint_as_float((unsigned)(127 - keB) << 23);
            rinvA = updA ? rnA : rinvA;
            rinvB = updB ? rnB : rinvB;
            kcurA = updA ? keA : kcurA;
            kcurB = updB ? keB : kcurB;
        }
    }

    // ---- epilogue 1: logz per batch ----
    float et = __expf(tstop); // tstop[STOP]=NEG -> 0
    float logzAB[2];
    {
        float peA = qA * et;
        float peB = qB * et;
#pragma unroll
        for (int w = 32; w >= 1; w >>= 1) {
            peA += __shfl_xor(peA, w, 64);
            peB += __shfl_xor(peB, w, 64);
        }
        logzAB[0] = __logf(peA) + C0A + (float)ktotA * 0.6931471805599453f;
        logzAB[1] = __logf(peB) + C0B + (float)ktotB * 0.6931471805599453f;
    }

    // ---- epilogue 2: true-path score; lanes parallel over time steps ----
#pragma unroll
    for (int bb = 0; bb < 2; ++bb) {
        const int bcur = 2 * bp + bb;
        float psc = 0.0f, pms = 0.0f;
#pragma unroll
        for (int k = 0; k < 8; ++k) {
            int s = j + 64 * k;
            int tg = tags[s * BATCH + bcur];
            float mk = (bb == 0) ? mrA[k] : mrB[k];
            int tprev = (s == 0) ? START_TAG : tags[(s - 1) * BATCH + bcur];
            float em = feats[((size_t)s * BATCH + bcur) * NTAG + tg];
            psc = fmaf(em + trans[tprev * NTAG + tg], mk, psc);
            pms += mk;
        }
#pragma unroll
        for (int w = 32; w >= 1; w >>= 1) {
            psc += __shfl_xor(psc, w, 64);
            pms += __shfl_xor(pms, w, 64);
        }
        if (j == 0) {
            int last_idx = (int)(pms + 0.5f) - 1;
            int ltag = tags[last_idx * BATCH + bcur];
            float score = psc + trans[ltag * NTAG + STOP_TAG];
            diff[bcur] = logzAB[bb] - score;
        }
    }
}

__global__ __launch_bounds__(512) void crf_reduce(const float* __restrict__ diff,
                                                  float* __restrict__ out) {
    __shared__ float sdata[8];
    int t = threadIdx.x;
    float val = diff[t];
#pragma unroll
    for (int w = 32; w >= 1; w >>= 1)
        val += __shfl_xor(val, w, 64);
    if ((t & 63) == 0) sdata[t >> 6] = val;
    __syncthreads();
    if (t == 0) {
        float ssum = 0.0f;
        for (int i = 0; i < 8; ++i) ssum += sdata[i];
        out[0] = ssum * (1.0f / (float)BATCH);
    }
}

extern "C" void kernel_launch(void* const* d_in, const int* in_sizes, int n_in,
                              void* d_out, int out_size, void* d_ws, size_t ws_size,
                              hipStream_t stream) {
    const float* feats = (const float*)d_in[0];
    const int* tags = (const int*)d_in[1];
    const float* mask = (const float*)d_in[2];
    const float* trans = (const float*)d_in[3];
    float* out = (float*)d_out;
    float* diff = (float*)d_ws; // 512 floats

    crf_fwd<<<BATCH / 2, 64, 0, stream>>>(feats, tags, mask, trans, diff);
    crf_reduce<<<1, 512, 0, stream>>>(diff, out);
}

// Round 5
// 226.172 us; speedup vs baseline: 1.7551x; 1.7551x over previous
//
#include <hip/hip_runtime.h>

#define NEG (-10000.0f)
#define START_TAG 62
#define STOP_TAG 63
#define SLEN 512
#define BATCH 512
#define NTAG 64

typedef float f32x2 __attribute__((ext_vector_type(2)));
typedef float f32x4 __attribute__((ext_vector_type(4)));

__device__ __forceinline__ float readlane_f(float v, int lane) {
    return __uint_as_float(__builtin_amdgcn_readlane(__float_as_uint(v), lane));
}

// One wave per batch; lane j = tag j.
//
// Round-9: round 8 (2-batch interleave) regressed 2.5x -> VGPR demand ~260 vs
// 132 allocated = scratch spill; cross-batch ILP abandoned for good. Back to
// the round-7 structure (125.8 us, chain ~590 cyc/step vs ~400 dataflow
// floor). The ~200 cyc excess is attributed to coarse lgkmcnt scheduling:
// compiler hoists all 16 ds_reads then drains before the FMA tree. Fix:
// MANUAL one-step-ahead DS pipelining -- after ds_write(q'), immediately
// issue next step's 16 ds_read_b128 into named regs Q[16] (same-wave DS pipe
// is in-order: reads follow the write), do all off-chain work (exp, global
// prefetch, renorm bookkeeping) under the DS latency, consume Q[r] in issue
// order next iteration. Mask read pipelined identically.
// Also: fused final reduction (last block via atomic ticket + device fences,
// bit-identical summation tree) -> second kernel launch eliminated.
//
// Exp-space recursion (verified round 7):
//   acc_j = sum_i q_i * E_ij  (v_pk_fma over e2 pairs)
//   q'_j  = acc_j * exp(f_j) * rinv,  rinv = 2^-k exact from prior acc[lane0]
//   logz  = log(sum_j q_j e^tstop_j) + C0 + ktot*ln2
__global__ __launch_bounds__(64) __attribute__((amdgpu_waves_per_eu(1, 1)))
void crf_fwd(const float* __restrict__ feats,
             const int* __restrict__ tags,
             const float* __restrict__ mask,
             const float* __restrict__ trans,
             float* __restrict__ diff /* [BATCH] */,
             float* __restrict__ out,
             unsigned* __restrict__ done) {
    const int b = blockIdx.x;
    const int j = threadIdx.x; // tag lane 0..63

    __shared__ float smask[SLEN + 1];             // +1: zero pad for mk pipeline
    __shared__ __align__(16) float qraw[2][NTAG]; // q ping-pong, 2x256B

    // ---- E pairs in registers: e2[r] = (exp(T[2r][j]), exp(T[2r+1][j])) ----
    f32x2 e2[32];
    float colsum = 0.0f;
#pragma unroll
    for (int r = 0; r < 32; ++r) {
        float lo = __expf(trans[(2 * r) * NTAG + j]);     // exp(NEG) -> 0, desired
        float hi = __expf(trans[(2 * r + 1) * NTAG + j]);
        e2[r] = (f32x2){lo, hi};
        colsum += lo + hi;
    }
    const float tstop = trans[STOP_TAG * NTAG + j];

    // ---- mask column preload (regs reused by epilogue 2) ----
    float mreg[8];
#pragma unroll
    for (int k = 0; k < 8; ++k) mreg[k] = mask[(64 * k + j) * BATCH + b];
#pragma unroll
    for (int k = 0; k < 8; ++k) smask[64 * k + j] = mreg[k];

    // ---- step 0 (exact analytic; trans[START,:]==NEG) ----
    float f_s0 = feats[(0 * BATCH + b) * NTAG + j];
    float m0 = readlane_f(mreg[0], 0);
    float alpha0 = (m0 > 0.0f) ? (NEG + log1pf(colsum) + f_s0)
                               : ((j == START_TAG) ? 0.0f : NEG);
    const float C0 = readlane_f(alpha0, START_TAG);
    float q = __expf(alpha0 - C0); // cold: exp(NEG)->0 except START lane = 1

    if (j == 0) { smask[0] = 0.0f; smask[SLEN] = 0.0f; } // s=0 masked no-op; pad
    qraw[0][j] = q;
    __syncthreads(); // single wave: cheap; orders LDS init before reads

    // ---- software-pipelined LDS state: Q holds qraw[ph] for current step ----
    f32x4 Q[16];
#pragma unroll
    for (int r = 0; r < 16; ++r) Q[r] = ((const f32x4*)&qraw[0][0])[r];
    float mk = smask[0]; // mask for step 0 (== 0.0f, dummy step)

    // ---- feats ring prefetch depth 8 (only vmcnt loads in the loop) ----
    const float* fp = feats + (size_t)b * NTAG + j;
    float fr[8];
#pragma unroll
    for (int t = 0; t < 8; ++t) fr[t] = fp[(size_t)t * BATCH * NTAG];

    float rinv = 1.0f; // wave-uniform pending normalizer 2^-kcur
    int kcur = 0;      // exponent embedded in rinv
    int ktot = 0;      // sum of APPLIED exponents

    for (int blk = 0; blk < 64; ++blk) {
#pragma unroll
        for (int t = 0; t < 8; ++t) {
            const int s = blk * 8 + t;
            const int ph = t & 1; // current buffer parity (blk*8 even)

            // ---- off-chain: exp(f), prefetch, scale prep (hide under DS) ----
            float ef = __expf(fr[t]); // operand loaded 8 steps ago
            int sp = s + 8;
            if (sp > SLEN - 1) sp = SLEN - 1; // tail garbage, never consumed
            fr[t] = fp[(size_t)sp * BATCH * NTAG];
            float efr = ef * rinv; // rinv known from last step

            // ---- FMA tree: consume Q[r] in ISSUE ORDER (incremental waits) --
            f32x2 acc[8];
#pragma unroll
            for (int r = 0; r < 16; ++r) {
                f32x2 qlo = (f32x2){Q[r].x, Q[r].y};
                f32x2 qhi = (f32x2){Q[r].z, Q[r].w};
                const int c0 = (2 * r) & 7, c1 = (2 * r + 1) & 7;
                if (r < 4) { // first touch: mul (no init pass)
                    acc[c0] = qlo * e2[2 * r];
                    acc[c1] = qhi * e2[2 * r + 1];
                } else {
                    acc[c0] = qlo * e2[2 * r] + acc[c0];         // v_pk_fma
                    acc[c1] = qhi * e2[2 * r + 1] + acc[c1];
                }
            }
            f32x2 s01 = (acc[0] + acc[1]) + (acc[2] + acc[3]);
            f32x2 s23 = (acc[4] + acc[5]) + (acc[6] + acc[7]);
            f32x2 sall = s01 + s23;
            float acc_s = sall.x + sall.y;

            float qn = acc_s * efr;
            bool upd = (mk > 0.0f);
            q = upd ? qn : q;    // masked step: q unchanged
            qraw[ph ^ 1][j] = q; // publish (in-order DS pipe)

            // ---- IMMEDIATELY issue next step's broadcast reads + mask ------
#pragma unroll
            for (int r = 0; r < 16; ++r)
                Q[r] = ((const f32x4*)&qraw[ph ^ 1][0])[r];
            mk = smask[s + 1]; // s=511 -> zero pad slot

            // ---- renormalizer bookkeeping (off the critical chain) ----
            ktot = upd ? (ktot + kcur) : ktot; // kcur was applied this step
            unsigned a0u = __builtin_amdgcn_readfirstlane(__float_as_uint(acc_s));
            int ke = (int)((a0u >> 23) & 0xffu) - 127; // floor exponent of acc[0]
            ke = (ke < -60) ? -60 : ((ke > 60) ? 60 : ke); // runaway guard
            float rnew = __uint_as_float((unsigned)(127 - ke) << 23); // exact 2^-ke
            rinv = upd ? rnew : rinv;
            kcur = upd ? ke : kcur;
        }
    }

    // ---- epilogue 1: logz = log(sum_j q_j * exp(tstop_j)) + C0 + ktot*ln2 ----
    float et = __expf(tstop); // tstop[STOP]=NEG -> 0; q[STOP]=0 anyway
    float pe = q * et;
#pragma unroll
    for (int w = 32; w >= 1; w >>= 1) pe += __shfl_xor(pe, w, 64);
    float logz = __logf(pe) + C0 + (float)ktot * 0.6931471805599453f;

    // ---- epilogue 2: true-path score; lanes parallel over time steps ----
    float psc = 0.0f, pms = 0.0f;
#pragma unroll
    for (int k = 0; k < 8; ++k) {
        int s = j + 64 * k;
        int tg = tags[s * BATCH + b];
        float mkk = mreg[k]; // this lane's preloaded mask[s]
        int tprev = (s == 0) ? START_TAG : tags[(s - 1) * BATCH + b];
        float em = feats[((size_t)s * BATCH + b) * NTAG + tg];
        psc = fmaf(em + trans[tprev * NTAG + tg], mkk, psc);
        pms += mkk;
    }
#pragma unroll
    for (int w = 32; w >= 1; w >>= 1) {
        psc += __shfl_xor(psc, w, 64);
        pms += __shfl_xor(pms, w, 64);
    }

    if (j == 0) {
        int last_idx = (int)(pms + 0.5f) - 1;
        int ltag = tags[last_idx * BATCH + b];
        float score = psc + trans[ltag * NTAG + STOP_TAG];
        diff[b] = logz - score;
    }

    // ---- fused reduction: last block to finish reduces diff[] ----
    __threadfence(); // release diff[b] to device scope
    unsigned ticket = 0;
    if (j == 0) ticket = atomicAdd(done, 1u);
    ticket = __builtin_amdgcn_readfirstlane(ticket);
    if (ticket == (unsigned)(gridDim.x - 1)) {
        __threadfence(); // acquire: see all blocks' diff stores
        float ssum = 0.0f;
#pragma unroll
        for (int w = 0; w < 8; ++w) {
            float val = diff[w * 64 + j];
#pragma unroll
            for (int x = 32; x >= 1; x >>= 1) val += __shfl_xor(val, x, 64);
            ssum += val; // same order as old crf_reduce: bit-identical
        }
        if (j == 0) out[0] = ssum * (1.0f / (float)BATCH);
    }
}

extern "C" void kernel_launch(void* const* d_in, const int* in_sizes, int n_in,
                              void* d_out, int out_size, void* d_ws, size_t ws_size,
                              hipStream_t stream) {
    const float* feats = (const float*)d_in[0];
    const int* tags = (const int*)d_in[1];
    const float* mask = (const float*)d_in[2];
    const float* trans = (const float*)d_in[3];
    float* out = (float*)d_out;
    float* diff = (float*)d_ws;                       // 512 floats
    unsigned* done = (unsigned*)((char*)d_ws + 2048); // ticket counter

    hipMemsetAsync(done, 0, sizeof(unsigned), stream); // graph-capturable
    crf_fwd<<<BATCH, 64, 0, stream>>>(feats, tags, mask, trans, diff, out, done);
}

// Round 7
// 225.823 us; speedup vs baseline: 1.7578x; 1.0015x over previous
//
#include <hip/hip_runtime.h>

#define NEG (-10000.0f)
#define START_TAG 62
#define STOP_TAG 63
#define SLEN 512
#define BATCH 512
#define NTAG 64

typedef float f32x2 __attribute__((ext_vector_type(2)));
typedef float f32x4 __attribute__((ext_vector_type(4)));

__device__ __forceinline__ float readlane_f(float v, int lane) {
    return __uint_as_float(__builtin_amdgcn_readlane(__float_as_uint(v), lane));
}

// One wave per batch; lane j = tag j.
//
// Round-11: round-10's bench died at container level with no diagnostics. The
// only source delta was combining __launch_bounds__(64) (which lowers to
// amdgpu-flat-work-group-size="1,64") with an explicit
// amdgpu_flat_work_group_size(64,64) -- a conflicting duplicate attribute that
// some toolchains hard-error on. Fix: drop __launch_bounds__, keep ONLY
// amdgpu_flat_work_group_size(64,64) + amdgpu_waves_per_eu(1,1). Device code
// otherwise byte-identical to the verified round-9 kernel (passed, absmax 0).
//
// Experiment (unchanged from round 10): round 9's manual one-step-ahead DS
// pipeline spilled (WRITE_SIZE 17->32 MB, VGPR pinned 132 vs ~165 demand);
// pinning the flat WG size should let waves_per_eu(1,1) unlock the full
// per-EU VGPR file. Key observables: VGPR_Count ~165-200, WRITE_SIZE ~17 MB;
// then crf_fwd fairly tests the manual schedule vs round 7's 125.8 us.
//
// Exp-space recursion (verified round 7):
//   acc_j = sum_i q_i * E_ij  (v_pk_fma over e2 pairs)
//   q'_j  = acc_j * exp(f_j) * rinv,  rinv = 2^-k exact from prior acc[lane0]
//   logz  = log(sum_j q_j e^tstop_j) + C0 + ktot*ln2
__global__
__attribute__((amdgpu_flat_work_group_size(64, 64), amdgpu_waves_per_eu(1, 1)))
void crf_fwd(const float* __restrict__ feats,
             const int* __restrict__ tags,
             const float* __restrict__ mask,
             const float* __restrict__ trans,
             float* __restrict__ diff /* [BATCH] */,
             float* __restrict__ out,
             unsigned* __restrict__ done) {
    const int b = blockIdx.x;
    const int j = threadIdx.x; // tag lane 0..63

    __shared__ float smask[SLEN + 1];             // +1: zero pad for mk pipeline
    __shared__ __align__(16) float qraw[2][NTAG]; // q ping-pong, 2x256B

    // ---- E pairs in registers: e2[r] = (exp(T[2r][j]), exp(T[2r+1][j])) ----
    f32x2 e2[32];
    float colsum = 0.0f;
#pragma unroll
    for (int r = 0; r < 32; ++r) {
        float lo = __expf(trans[(2 * r) * NTAG + j]);     // exp(NEG) -> 0, desired
        float hi = __expf(trans[(2 * r + 1) * NTAG + j]);
        e2[r] = (f32x2){lo, hi};
        colsum += lo + hi;
    }
    const float tstop = trans[STOP_TAG * NTAG + j];

    // ---- mask column preload (regs reused by epilogue 2) ----
    float mreg[8];
#pragma unroll
    for (int k = 0; k < 8; ++k) mreg[k] = mask[(64 * k + j) * BATCH + b];
#pragma unroll
    for (int k = 0; k < 8; ++k) smask[64 * k + j] = mreg[k];

    // ---- step 0 (exact analytic; trans[START,:]==NEG) ----
    float f_s0 = feats[(0 * BATCH + b) * NTAG + j];
    float m0 = readlane_f(mreg[0], 0);
    float alpha0 = (m0 > 0.0f) ? (NEG + log1pf(colsum) + f_s0)
                               : ((j == START_TAG) ? 0.0f : NEG);
    const float C0 = readlane_f(alpha0, START_TAG);
    float q = __expf(alpha0 - C0); // cold: exp(NEG)->0 except START lane = 1

    if (j == 0) { smask[0] = 0.0f; smask[SLEN] = 0.0f; } // s=0 masked no-op; pad
    qraw[0][j] = q;
    __syncthreads(); // single wave: cheap; orders LDS init before reads

    // ---- software-pipelined LDS state: Q holds qraw[ph] for current step ----
    f32x4 Q[16];
#pragma unroll
    for (int r = 0; r < 16; ++r) Q[r] = ((const f32x4*)&qraw[0][0])[r];
    float mk = smask[0]; // mask for step 0 (== 0.0f, dummy step)

    // ---- feats ring prefetch depth 8 (only vmcnt loads in the loop) ----
    const float* fp = feats + (size_t)b * NTAG + j;
    float fr[8];
#pragma unroll
    for (int t = 0; t < 8; ++t) fr[t] = fp[(size_t)t * BATCH * NTAG];

    float rinv = 1.0f; // wave-uniform pending normalizer 2^-kcur
    int kcur = 0;      // exponent embedded in rinv
    int ktot = 0;      // sum of APPLIED exponents

    for (int blk = 0; blk < 64; ++blk) {
#pragma unroll
        for (int t = 0; t < 8; ++t) {
            const int s = blk * 8 + t;
            const int ph = t & 1; // current buffer parity (blk*8 even)

            // ---- off-chain: exp(f), prefetch, scale prep (hide under DS) ----
            float ef = __expf(fr[t]); // operand loaded 8 steps ago
            int sp = s + 8;
            if (sp > SLEN - 1) sp = SLEN - 1; // tail garbage, never consumed
            fr[t] = fp[(size_t)sp * BATCH * NTAG];
            float efr = ef * rinv; // rinv known from last step

            // ---- FMA tree: consume Q[r] in ISSUE ORDER (incremental waits) --
            f32x2 acc[8];
#pragma unroll
            for (int r = 0; r < 16; ++r) {
                f32x2 qlo = (f32x2){Q[r].x, Q[r].y};
                f32x2 qhi = (f32x2){Q[r].z, Q[r].w};
                const int c0 = (2 * r) & 7, c1 = (2 * r + 1) & 7;
                if (r < 4) { // first touch: mul (no init pass)
                    acc[c0] = qlo * e2[2 * r];
                    acc[c1] = qhi * e2[2 * r + 1];
                } else {
                    acc[c0] = qlo * e2[2 * r] + acc[c0];         // v_pk_fma
                    acc[c1] = qhi * e2[2 * r + 1] + acc[c1];
                }
            }
            f32x2 s01 = (acc[0] + acc[1]) + (acc[2] + acc[3]);
            f32x2 s23 = (acc[4] + acc[5]) + (acc[6] + acc[7]);
            f32x2 sall = s01 + s23;
            float acc_s = sall.x + sall.y;

            float qn = acc_s * efr;
            bool upd = (mk > 0.0f);
            q = upd ? qn : q;    // masked step: q unchanged
            qraw[ph ^ 1][j] = q; // publish (in-order DS pipe)

            // ---- IMMEDIATELY issue next step's broadcast reads + mask ------
#pragma unroll
            for (int r = 0; r < 16; ++r)
                Q[r] = ((const f32x4*)&qraw[ph ^ 1][0])[r];
            mk = smask[s + 1]; // s=511 -> zero pad slot

            // ---- renormalizer bookkeeping (off the critical chain) ----
            ktot = upd ? (ktot + kcur) : ktot; // kcur was applied this step
            unsigned a0u = __builtin_amdgcn_readfirstlane(__float_as_uint(acc_s));
            int ke = (int)((a0u >> 23) & 0xffu) - 127; // floor exponent of acc[0]
            ke = (ke < -60) ? -60 : ((ke > 60) ? 60 : ke); // runaway guard
            float rnew = __uint_as_float((unsigned)(127 - ke) << 23); // exact 2^-ke
            rinv = upd ? rnew : rinv;
            kcur = upd ? ke : kcur;
        }
    }

    // ---- epilogue 1: logz = log(sum_j q_j * exp(tstop_j)) + C0 + ktot*ln2 ----
    float et = __expf(tstop); // tstop[STOP]=NEG -> 0; q[STOP]=0 anyway
    float pe = q * et;
#pragma unroll
    for (int w = 32; w >= 1; w >>= 1) pe += __shfl_xor(pe, w, 64);
    float logz = __logf(pe) + C0 + (float)ktot * 0.6931471805599453f;

    // ---- epilogue 2: true-path score; lanes parallel over time steps ----
    float psc = 0.0f, pms = 0.0f;
#pragma unroll
    for (int k = 0; k < 8; ++k) {
        int s = j + 64 * k;
        int tg = tags[s * BATCH + b];
        float mkk = mreg[k]; // this lane's preloaded mask[s]
        int tprev = (s == 0) ? START_TAG : tags[(s - 1) * BATCH + b];
        float em = feats[((size_t)s * BATCH + b) * NTAG + tg];
        psc = fmaf(em + trans[tprev * NTAG + tg], mkk, psc);
        pms += mkk;
    }
#pragma unroll
    for (int w = 32; w >= 1; w >>= 1) {
        psc += __shfl_xor(psc, w, 64);
        pms += __shfl_xor(pms, w, 64);
    }

    if (j == 0) {
        int last_idx = (int)(pms + 0.5f) - 1;
        int ltag = tags[last_idx * BATCH + b];
        float score = psc + trans[ltag * NTAG + STOP_TAG];
        diff[b] = logz - score;
    }

    // ---- fused reduction: last block to finish reduces diff[] ----
    __threadfence(); // release diff[b] to device scope
    unsigned ticket = 0;
    if (j == 0) ticket = atomicAdd(done, 1u);
    ticket = __builtin_amdgcn_readfirstlane(ticket);
    if (ticket == (unsigned)(gridDim.x - 1)) {
        __threadfence(); // acquire: see all blocks' diff stores
        float ssum = 0.0f;
#pragma unroll
        for (int w = 0; w < 8; ++w) {
            float val = diff[w * 64 + j];
#pragma unroll
            for (int x = 32; x >= 1; x >>= 1) val += __shfl_xor(val, x, 64);
            ssum += val; // same order as old crf_reduce: bit-identical
        }
        if (j == 0) out[0] = ssum * (1.0f / (float)BATCH);
    }
}

extern "C" void kernel_launch(void* const* d_in, const int* in_sizes, int n_in,
                              void* d_out, int out_size, void* d_ws, size_t ws_size,
                              hipStream_t stream) {
    const float* feats = (const float*)d_in[0];
    const int* tags = (const int*)d_in[1];
    const float* mask = (const float*)d_in[2];
    const float* trans = (const float*)d_in[3];
    float* out = (float*)d_out;
    float* diff = (float*)d_ws;                       // 512 floats
    unsigned* done = (unsigned*)((char*)d_ws + 2048); // ticket counter

    hipMemsetAsync(done, 0, sizeof(unsigned), stream); // graph-capturable
    crf_fwd<<<BATCH, 64, 0, stream>>>(feats, tags, mask, trans, diff, out, done);
}

// Round 8
// 201.239 us; speedup vs baseline: 1.9726x; 1.1222x over previous
//
#include <hip/hip_runtime.h>

#define NEG (-10000.0f)
#define START_TAG 62
#define STOP_TAG 63
#define SLEN 512
#define BATCH 512
#define NTAG 64

typedef float f32x2 __attribute__((ext_vector_type(2)));
typedef float f32x4 __attribute__((ext_vector_type(4)));

__device__ __forceinline__ float readlane_f(float v, int lane) {
    return __uint_as_float(__builtin_amdgcn_readlane(__float_as_uint(v), lane));
}

// One wave per batch; lane j = tag j.
//
// Round-12: allocator is hard-capped at 132 VGPRs (waves_per_eu + flat_wg_size
// both failed to raise it; Q[16] lookahead spills). New plan fits the pipeline
// into the cap: 4-chunk (16-float) lookahead issued right after the q' write
// (+16 regs), remaining 12 chunks read in 2-chunk groups interleaved with the
// FMA tree (peak extra live ~24-32). Paid for by: feats ring 8->2 (R1 showed
// depth-2 suffices), mask regs dropped (epilogue reloads from global),
// accumulators 8->4. Target: remove the ~130cy exposed ds_read return latency
// from R3's 590 cyc/step chain.
//
// Exp-space recursion (verified rounds 7-11):
//   acc_j = sum_i q_i * E_ij  (v_pk_fma over e2 pairs)
//   q'_j  = acc_j * exp(f_j) * rinv,  rinv = 2^-k exact from prior acc[lane0]
//   logz  = log(sum_j q_j e^tstop_j) + C0 + ktot*ln2
__global__ __launch_bounds__(64) __attribute__((amdgpu_waves_per_eu(1, 1)))
void crf_fwd(const float* __restrict__ feats,
             const int* __restrict__ tags,
             const float* __restrict__ mask,
             const float* __restrict__ trans,
             float* __restrict__ diff /* [BATCH] */) {
    const int b = blockIdx.x;
    const int j = threadIdx.x; // tag lane 0..63

    __shared__ float smask[SLEN];                 // wave-uniform mask column
    __shared__ __align__(16) float qraw[2][NTAG]; // q ping-pong, 2x256B

    // ---- E pairs in registers: e2[r] = (exp(T[2r][j]), exp(T[2r+1][j])) ----
    f32x2 e2[32];
    float colsum = 0.0f;
#pragma unroll
    for (int r = 0; r < 32; ++r) {
        float lo = __expf(trans[(2 * r) * NTAG + j]);     // exp(NEG) -> 0, desired
        float hi = __expf(trans[(2 * r + 1) * NTAG + j]);
        e2[r] = (f32x2){lo, hi};
        colsum += lo + hi;
    }
    const float tstop = trans[STOP_TAG * NTAG + j];

    // ---- mask column -> LDS (no persistent regs; epilogue reloads global) --
#pragma unroll
    for (int k = 0; k < 8; ++k)
        smask[64 * k + j] = mask[(64 * k + j) * BATCH + b];

    // ---- step 0 (exact analytic; trans[START,:]==NEG) ----
    float f_s0 = feats[(size_t)b * NTAG + j]; // feats[0][b][j]
    float m0 = mask[b];                       // mask[0][b], wave-uniform
    float alpha0 = (m0 > 0.0f) ? (NEG + log1pf(colsum) + f_s0)
                               : ((j == START_TAG) ? 0.0f : NEG);
    const float CC0 = readlane_f(alpha0, START_TAG);
    float q = __expf(alpha0 - CC0); // cold: exp(NEG)->0 except START lane = 1

    if (j == 0) smask[0] = 0.0f; // s=0 loop iteration is a masked no-op
    qraw[0][j] = q;
    __syncthreads(); // single wave: cheap; orders LDS init before reads

    // ---- feats prefetch depth 2 ----
    const float* fp = feats + (size_t)b * NTAG + j;
    float f0 = f_s0; // consumed (masked off) by dummy step 0
    float f1 = fp[(size_t)1 * BATCH * NTAG];

    // ---- lookahead: first 4 chunks (16 floats) of current q buffer ----
    f32x4 la0 = ((const f32x4*)&qraw[0][0])[0];
    f32x4 la1 = ((const f32x4*)&qraw[0][0])[1];
    f32x4 lb0 = ((const f32x4*)&qraw[0][0])[2];
    f32x4 lb1 = ((const f32x4*)&qraw[0][0])[3];

    float rinv = 1.0f; // wave-uniform pending normalizer 2^-kcur
    int kcur = 0;      // exponent embedded in rinv
    int ktot = 0;      // sum of APPLIED exponents

#define STEP(S_, PH_)                                                          \
    {                                                                          \
        const int s_ = (S_);                                                   \
        const f32x4* qv = (const f32x4*)&qraw[(PH_)][0];                       \
        float mk = smask[s_];                                                  \
        float ef = __expf(f0);                                                 \
        f0 = f1;                                                               \
        int sp_ = s_ + 2;                                                      \
        if (sp_ > SLEN - 1) sp_ = SLEN - 1; /* tail garbage, never consumed */ \
        f1 = fp[(size_t)sp_ * (BATCH * NTAG)];                                 \
        float efr = ef * rinv; /* rinv known from last step */                 \
        /* rolling reads interleaved with tree; lookahead chunks are ready */  \
        f32x4 gc0 = qv[4], gc1 = qv[5];                                        \
        f32x2 acc0 = (f32x2){la0.x, la0.y} * e2[0];                            \
        f32x2 acc1 = (f32x2){la0.z, la0.w} * e2[1];                            \
        f32x2 acc2 = (f32x2){la1.x, la1.y} * e2[2];                            \
        f32x2 acc3 = (f32x2){la1.z, la1.w} * e2[3];                            \
        f32x4 gd0 = qv[6], gd1 = qv[7];                                        \
        acc0 = (f32x2){lb0.x, lb0.y} * e2[4] + acc0;                           \
        acc1 = (f32x2){lb0.z, lb0.w} * e2[5] + acc1;                           \
        acc2 = (f32x2){lb1.x, lb1.y} * e2[6] + acc2;                           \
        acc3 = (f32x2){lb1.z, lb1.w} * e2[7] + acc3;                           \
        f32x4 ge0 = qv[8], ge1 = qv[9];                                        \
        acc0 = (f32x2){gc0.x, gc0.y} * e2[8] + acc0;                           \
        acc1 = (f32x2){gc0.z, gc0.w} * e2[9] + acc1;                           \
        acc2 = (f32x2){gc1.x, gc1.y} * e2[10] + acc2;                          \
        acc3 = (f32x2){gc1.z, gc1.w} * e2[11] + acc3;                          \
        f32x4 gf0 = qv[10], gf1 = qv[11];                                      \
        acc0 = (f32x2){gd0.x, gd0.y} * e2[12] + acc0;                          \
        acc1 = (f32x2){gd0.z, gd0.w} * e2[13] + acc1;                          \
        acc2 = (f32x2){gd1.x, gd1.y} * e2[14] + acc2;                          \
        acc3 = (f32x2){gd1.z, gd1.w} * e2[15] + acc3;                          \
        f32x4 gg0 = qv[12], gg1 = qv[13];                                      \
        acc0 = (f32x2){ge0.x, ge0.y} * e2[16] + acc0;                          \
        acc1 = (f32x2){ge0.z, ge0.w} * e2[17] + acc1;                          \
        acc2 = (f32x2){ge1.x, ge1.y} * e2[18] + acc2;                          \
        acc3 = (f32x2){ge1.z, ge1.w} * e2[19] + acc3;                          \
        f32x4 gh0 = qv[14], gh1 = qv[15];                                      \
        acc0 = (f32x2){gf0.x, gf0.y} * e2[20] + acc0;                          \
        acc1 = (f32x2){gf0.z, gf0.w} * e2[21] + acc1;                          \
        acc2 = (f32x2){gf1.x, gf1.y} * e2[22] + acc2;                          \
        acc3 = (f32x2){gf1.z, gf1.w} * e2[23] + acc3;                          \
        acc0 = (f32x2){gg0.x, gg0.y} * e2[24] + acc0;                          \
        acc1 = (f32x2){gg0.z, gg0.w} * e2[25] + acc1;                          \
        acc2 = (f32x2){gg1.x, gg1.y} * e2[26] + acc2;                          \
        acc3 = (f32x2){gg1.z, gg1.w} * e2[27] + acc3;                          \
        acc0 = (f32x2){gh0.x, gh0.y} * e2[28] + acc0;                          \
        acc1 = (f32x2){gh0.z, gh0.w} * e2[29] + acc1;                          \
        acc2 = (f32x2){gh1.x, gh1.y} * e2[30] + acc2;                          \
        acc3 = (f32x2){gh1.z, gh1.w} * e2[31] + acc3;                          \
        f32x2 rr = (acc0 + acc1) + (acc2 + acc3);                              \
        float acc_s = rr.x + rr.y;                                             \
        float qn = acc_s * efr;                                                \
        bool upd = (mk > 0.0f);                                                \
        q = upd ? qn : q;          /* masked step: q unchanged */              \
        qraw[(PH_) ^ 1][j] = q;    /* publish (in-order DS pipe) */            \
        /* issue next step's lookahead immediately after the write */          \
        {                                                                      \
            const f32x4* qw = (const f32x4*)&qraw[(PH_) ^ 1][0];               \
            la0 = qw[0]; la1 = qw[1]; lb0 = qw[2]; lb1 = qw[3];                \
        }                                                                      \
        /* renorm bookkeeping (off the critical chain) */                      \
        ktot = upd ? (ktot + kcur) : ktot;                                     \
        unsigned a0u = __builtin_amdgcn_readfirstlane(__float_as_uint(acc_s)); \
        int ke = (int)((a0u >> 23) & 0xffu) - 127;                             \
        ke = (ke < -60) ? -60 : ((ke > 60) ? 60 : ke);                         \
        float rnew = __uint_as_float((unsigned)(127 - ke) << 23);              \
        rinv = upd ? rnew : rinv;                                              \
        kcur = upd ? ke : kcur;                                                \
    }

    for (int s2 = 0; s2 < SLEN; s2 += 2) {
        STEP(s2, 0);
        STEP(s2 + 1, 1);
    }
#undef STEP

    // ---- epilogue 1: logz = log(sum_j q_j * exp(tstop_j)) + C0 + ktot*ln2 ----
    float et = __expf(tstop); // tstop[STOP]=NEG -> 0; q[STOP]=0 anyway
    float pe = q * et;
#pragma unroll
    for (int w = 32; w >= 1; w >>= 1) pe += __shfl_xor(pe, w, 64);
    float logz = __logf(pe) + CC0 + (float)ktot * 0.6931471805599453f;

    // ---- epilogue 2: true-path score; lanes parallel over time steps ----
    float psc = 0.0f, pms = 0.0f;
#pragma unroll
    for (int k = 0; k < 8; ++k) {
        int s = j + 64 * k;
        int tg = tags[s * BATCH + b];
        float mkk = mask[(64 * k + j) * BATCH + b]; // reload (off perf path)
        int tprev = (s == 0) ? START_TAG : tags[(s - 1) * BATCH + b];
        float em = feats[((size_t)s * BATCH + b) * NTAG + tg];
        psc = fmaf(em + trans[tprev * NTAG + tg], mkk, psc);
        pms += mkk;
    }
#pragma unroll
    for (int w = 32; w >= 1; w >>= 1) {
        psc += __shfl_xor(psc, w, 64);
        pms += __shfl_xor(pms, w, 64);
    }

    if (j == 0) {
        int last_idx = (int)(pms + 0.5f) - 1;
        int ltag = tags[last_idx * BATCH + b];
        float score = psc + trans[ltag * NTAG + STOP_TAG];
        diff[b] = logz - score;
    }
}

__global__ __launch_bounds__(512) void crf_reduce(const float* __restrict__ diff,
                                                  float* __restrict__ out) {
    __shared__ float sdata[8];
    int t = threadIdx.x;
    float val = diff[t];
#pragma unroll
    for (int w = 32; w >= 1; w >>= 1)
        val += __shfl_xor(val, w, 64);
    if ((t & 63) == 0) sdata[t >> 6] = val;
    __syncthreads();
    if (t == 0) {
        float ssum = 0.0f;
        for (int i = 0; i < 8; ++i) ssum += sdata[i];
        out[0] = ssum * (1.0f / (float)BATCH);
    }
}

extern "C" void kernel_launch(void* const* d_in, const int* in_sizes, int n_in,
                              void* d_out, int out_size, void* d_ws, size_t ws_size,
                              hipStream_t stream) {
    const float* feats = (const float*)d_in[0];
    const int* tags = (const int*)d_in[1];
    const float* mask = (const float*)d_in[2];
    const float* trans = (const float*)d_in[3];
    float* out = (float*)d_out;
    float* diff = (float*)d_ws; // 512 floats

    crf_fwd<<<BATCH, 64, 0, stream>>>(feats, tags, mask, trans, diff);
    crf_reduce<<<1, 512, 0, stream>>>(diff, out);
}